// Round 4
// baseline (407.379 us; speedup 1.0000x reference)
//
#include <hip/hip_runtime.h>

#define TT 512
#define BB 256
#define DD 128
#define HH 128
#define QQ 8

struct Params {
    const float* x;
    const float* W[4];
    const float* b[4];
    const float* th[4];
    const float* U[4];
    const float* cb[4];
    float* out;
};

__device__ __forceinline__ float sigm_fast(float x) {
    return __builtin_amdgcn_rcpf(1.f + __expf(-x));
}
__device__ __forceinline__ float tanh_fast(float x) {
    // 1 - 2/(e^{2x}+1); saturates correctly at +-inf
    return 1.f - 2.f * __builtin_amdgcn_rcpf(__expf(2.f * x) + 1.f);
}
template<int CTRL>
__device__ __forceinline__ float dpp_mov(float x) {
    int r = __builtin_amdgcn_update_dpp(0, __float_as_int(x), CTRL, 0xF, 0xF, true);
    return __int_as_float(r);
}
// Workgroup barrier that does NOT drain vmcnt (global loads/stores stay in
// flight across it). LDS ordering only: s_waitcnt lgkmcnt(0) + s_barrier.
// __syncthreads() would emit s_waitcnt vmcnt(0) and put every global store /
// x-prefetch on the per-step critical path.
__device__ __forceinline__ void bar_lds() {
    asm volatile("s_waitcnt lgkmcnt(0)\n\ts_barrier" ::: "memory");
}

// One block per batch element. 256 threads = 4 waves; wave w owns gate w
// (order f,i,g,o). Thread = (gate=wv, qubit=(tid>>3)&7, part=tid&7).
// LDS pad: slot(k) = k + 4*(k>>5) -> conflict-free + 16B-aligned b128 reads.
__global__ __launch_bounds__(256, 1) void qlstm(Params p) {
    __shared__ __align__(16) float xbuf[2][8][144]; // staged x rows (padded)
    __shared__ __align__(16) float hbuf[144];       // h_{t-1} (padded)
    __shared__ float pre[512];                      // gate preactivations

    const int tid = threadIdx.x;
    const int bId = blockIdx.x;
    const int ln  = tid & 63;        // lane in wave
    const int wv  = tid >> 6;        // wave id == gate id
    const int qub = (tid >> 3) & 7;  // qubit
    const int part = tid & 7;        // k-slice

    // ---- constant per-thread registers ----
    float Wreg[32];
    {
        const float* Wg = p.W[wv] + qub * (DD + HH) + part * 32;
        #pragma unroll
        for (int j = 0; j < 32; ++j) Wreg[j] = Wg[j];
    }
    const float breg  = p.b[wv][qub] + p.th[wv][qub];  // fused bias+theta

    // U-phase: wave wv computes gate wv preacts for h0=ln, h1=ln+64
    float Ua[8], Ub[8];
    #pragma unroll
    for (int j = 0; j < 8; ++j) {
        Ua[j] = p.U[wv][ln * QQ + j];
        Ub[j] = p.U[wv][(ln + 64) * QQ + j];
    }
    const float cba = p.cb[wv][ln];
    const float cbb = p.cb[wv][ln + 64];

    float cst = 0.f;      // cell state, owned by tid<128 (h=tid)
    float hn_last = 0.f;  // last h, kept in-register for the tail stores

    if (tid < 128) hbuf[tid + 4 * (tid >> 5)] = 0.f;

    // ---- x chunk staging: wave 3. Lane covers col=(ln&31)*4, rows 2j+(ln>>5) ----
    const int xc_col  = (ln & 31) * 4;   // 0..124, step 4
    const int xc_half = ln >> 5;         // 0/1
    const int xc_slot = xc_col + 4 * (xc_col >> 5);
    float4 xr[4];
    #pragma unroll
    for (int j = 0; j < 4; ++j) xr[j] = make_float4(0.f, 0.f, 0.f, 0.f);

    if (wv == 3) {
        // chunk 0 (steps 0..7) -> xbuf[0], synchronous
        #pragma unroll
        for (int j = 0; j < 4; ++j) {
            const int row = 2 * j + xc_half;
            float4 v = *(const float4*)(p.x + ((size_t)row * BB + bId) * DD + xc_col);
            *(float4*)&xbuf[0][row][xc_slot] = v;
        }
        // issue chunk 1 (steps 8..15), consumed at E of step 7
        #pragma unroll
        for (int j = 0; j < 4; ++j) {
            const int row = 8 + 2 * j + xc_half;
            xr[j] = *(const float4*)(p.x + ((size_t)row * BB + bId) * DD + xc_col);
        }
    }
    __syncthreads();   // init barrier: full drain is fine here (once)

    for (int t = 0; t < TT; ++t) {
        // ---- issue next x chunk (8 steps of genuine slack now) ----
        if (((t & 7) == 0) && wv == 3) {
            const int tch = (t >> 3) + 1;
            if (tch < TT / 8) {
                #pragma unroll
                for (int j = 0; j < 4; ++j) {
                    const int row = tch * 8 + 2 * j + xc_half;
                    xr[j] = *(const float4*)(p.x + ((size_t)row * BB + bId) * DD + xc_col);
                }
            }
        }

        // ---- Z: z[g][q] = W[g][q] . [x_t, h_{t-1}]  (8x b128, 4-acc FMA) ----
        const float* src = (part < 4) ? &xbuf[(t >> 3) & 1][t & 7][36 * part]
                                      : &hbuf[36 * (part - 4)];
        float a0 = 0.f, a1 = 0.f, a2 = 0.f, a3 = 0.f;
        #pragma unroll
        for (int j4 = 0; j4 < 8; ++j4) {
            float4 c4 = *(const float4*)(src + 4 * j4);
            a0 = fmaf(Wreg[4*j4+0], c4.x, a0);
            a1 = fmaf(Wreg[4*j4+1], c4.y, a1);
            a2 = fmaf(Wreg[4*j4+2], c4.z, a2);
            a3 = fmaf(Wreg[4*j4+3], c4.w, a3);
        }
        float acc = (a0 + a1) + (a2 + a3);

        // 8-lane reduction via DPP butterflies (VALU speed, no DS)
        acc += dpp_mov<0xB1>(acc);    // quad_perm(1,0,3,2): xor 1
        acc += dpp_mov<0x4E>(acc);    // quad_perm(2,3,0,1): xor 2
        acc += dpp_mov<0x141>(acc);   // row_half_mirror:    xor 4 (within 8)

        // ---- Qgate: cos, single bpermute round, local cumprods ----
        const float cv = __cosf(acc + breg);   // all 8 lanes of octet hold c_q
        float c[8];
        #pragma unroll
        for (int j = 0; j < 8; ++j) {
            c[j] = __int_as_float(
                __builtin_amdgcn_ds_bpermute(j * 32, __float_as_int(cv)));
        }
        const float q1 = c[0] * c[1];
        const float q2 = q1 * c[2];
        const float q3 = q2 * c[3];
        const float q4 = q3 * c[4];
        const float q5 = q4 * c[5];
        const float q6 = q5 * c[6];
        const float q7 = q6 * c[7];
        float q0 = c[1] * c[2];
        q0 *= c[3]; q0 *= c[4]; q0 *= c[5]; q0 *= c[6]; q0 *= c[7];

        // ---- U expansion: pre[gate][h] ----
        float pa = fmaf(Ua[0], q0, cba); float pb = fmaf(Ub[0], q0, cbb);
        pa = fmaf(Ua[1], q1, pa);        pb = fmaf(Ub[1], q1, pb);
        pa = fmaf(Ua[2], q2, pa);        pb = fmaf(Ub[2], q2, pb);
        pa = fmaf(Ua[3], q3, pa);        pb = fmaf(Ub[3], q3, pb);
        pa = fmaf(Ua[4], q4, pa);        pb = fmaf(Ub[4], q4, pb);
        pa = fmaf(Ua[5], q5, pa);        pb = fmaf(Ub[5], q5, pb);
        pa = fmaf(Ua[6], q6, pa);        pb = fmaf(Ub[6], q6, pb);
        pa = fmaf(Ua[7], q7, pa);        pb = fmaf(Ub[7], q7, pb);
        pre[wv * 128 + ln]      = pa;
        pre[wv * 128 + 64 + ln] = pb;

        bar_lds();   // barrier 1: pre[] ready (no vmem drain)

        // ---- E: cell update + out store (waves 0-1), x LDS write (wave 3) ----
        if (tid < 128) {
            float fg = sigm_fast(pre[tid]);
            float ig = sigm_fast(pre[128 + tid]);
            float gg = tanh_fast(pre[256 + tid]);
            float og = sigm_fast(pre[384 + tid]);
            cst = fmaf(fg, cst, ig * gg);
            float hn = og * tanh_fast(cst);
            hn_last = hn;
            hbuf[tid + 4 * (tid >> 5)] = hn;
            p.out[(size_t)(t * BB + bId) * HH + tid] = hn;  // issue-only now
        } else if (wv == 3 && (t & 7) == 7) {
            const int tch = (t >> 3) + 1;
            if (tch < TT / 8) {
                #pragma unroll
                for (int j = 0; j < 4; ++j) {
                    const int row = 2 * j + xc_half;
                    *(float4*)&xbuf[tch & 1][row][xc_slot] = xr[j];
                }
            }
        }
        bar_lds();   // barrier 2: hbuf / xbuf ready (no vmem drain)
    }

    // ---- tail: hx, cx ----
    if (tid < 128) {
        p.out[(size_t)TT * BB * HH + (size_t)bId * HH + tid] = hn_last;
        p.out[(size_t)TT * BB * HH + (size_t)BB * HH + (size_t)bId * HH + tid] = cst;
    }
}

extern "C" void kernel_launch(void* const* d_in, const int* in_sizes, int n_in,
                              void* d_out, int out_size, void* d_ws, size_t ws_size,
                              hipStream_t stream) {
    (void)in_sizes; (void)n_in; (void)out_size; (void)d_ws; (void)ws_size;
    Params p;
    p.x = (const float*)d_in[0];
    for (int g = 0; g < 4; ++g) {
        p.W[g]  = (const float*)d_in[1 + 5 * g + 0];
        p.b[g]  = (const float*)d_in[1 + 5 * g + 1];
        p.th[g] = (const float*)d_in[1 + 5 * g + 2];
        p.U[g]  = (const float*)d_in[1 + 5 * g + 3];
        p.cb[g] = (const float*)d_in[1 + 5 * g + 4];
    }
    p.out = (float*)d_out;
    hipLaunchKernelGGL(qlstm, dim3(BB), dim3(256), 0, stream, p);
}

// Round 5
// 371.007 us; speedup vs baseline: 1.0980x; 1.0980x over previous
//
#include <hip/hip_runtime.h>

#define TT 512
#define BB 256
#define DD 128
#define HH 128
#define QQ 8

struct Params {
    const float* x;
    const float* W[4];
    const float* b[4];
    const float* th[4];
    const float* U[4];
    const float* cb[4];
    float* out;
};

__device__ __forceinline__ float rcp_f(float x)  { return __builtin_amdgcn_rcpf(x); }
__device__ __forceinline__ float exp2_f(float x) { return __builtin_amdgcn_exp2f(x); }

// DPP move for sum-butterflies (old=0, bound_ctrl=on; all lanes valid for xor perms)
template<int CTRL>
__device__ __forceinline__ float dpp_mov(float x) {
    int r = __builtin_amdgcn_update_dpp(0, __float_as_int(x), CTRL, 0xF, 0xF, true);
    return __int_as_float(r);
}
// DPP with multiplicative-identity fallback: masked/invalid lanes receive 1.0f.
template<int CTRL, int RM>
__device__ __forceinline__ float dpp_mul1(float x) {
    int r = __builtin_amdgcn_update_dpp(0x3f800000 /*1.0f*/, __float_as_int(x),
                                        CTRL, RM, 0xF, false);
    return __int_as_float(r);
}
#define RDLANE(v, l) __int_as_float(__builtin_amdgcn_readlane(__float_as_int(v), (l)))

// Barrier without vmcnt drain (LDS ordering only) — global loads/stores stay in flight.
__device__ __forceinline__ void bar_lds() {
    asm volatile("s_waitcnt lgkmcnt(0)\n\ts_barrier" ::: "memory");
}

// One block per batch element; 4 waves; wave w owns gate w (f,i,g,o).
// Z-phase thread = (gate=wv, qubit=ln>>3, part8=ln&7) over the h-half only;
// the x-half (zx) is pipelined: computed for step t+1 by waves 2-3 during E(t).
// LDS pad: slot(k) = k + 4*(k>>5) -> conflict-free + 16B-aligned b128 slices.
__global__ __launch_bounds__(256, 1) void qlstm(Params p) {
    __shared__ __align__(16) float xbuf[2][8][144]; // staged x rows (padded)
    __shared__ __align__(16) float hbuf[144];       // h_{t-1} (padded)
    __shared__ float pre[512];                      // gate preactivations (scaled)
    __shared__ float zxbuf[2][32];                  // pipelined x-half of z

    const int tid = threadIdx.x;
    const int bId = blockIdx.x;
    const int ln  = tid & 63;
    const int wv  = tid >> 6;        // wave id == gate id
    const int qub = ln >> 3;         // qubit (octet)
    const int part8 = ln & 7;        // 16-float h-slice

    // ---- zh weights: W[wv][qub][128 + 16*part8 + j] ----
    float Wh[16];
    {
        const float* Wg = p.W[wv] + qub * (DD + HH) + DD + part8 * 16;
        #pragma unroll
        for (int j = 0; j < 16; ++j) Wh[j] = Wg[j];
    }
    const float breg = p.b[wv][qub] + p.th[wv][qub];  // fused bias+theta

    // ---- zx weights (waves 2-3): gate gz, qubit qz, 32-float x-slice pz ----
    const int gz = 2 * (wv - 2) + (ln >> 5);
    const int qz = (ln >> 2) & 7;
    const int pz = ln & 3;
    float Wx[32];
    if (wv >= 2) {
        const float* Wg = p.W[gz] + qz * (DD + HH) + pz * 32;
        #pragma unroll
        for (int j = 0; j < 32; ++j) Wx[j] = Wg[j];
    }

    // ---- U expansion constants, pre-scaled for exp2-based activations ----
    // gates f,i,o: pre' = -log2e * pre  -> sigm = rcp(1+exp2(pre'))
    // gate  g    : pre' = 2*log2e * pre -> tanh = 1 - 2*rcp(1+exp2(pre'))
    const float esc = (wv == 2) ? 2.885390081777927f : -1.442695040888963f;
    float Ua[8], Ub[8];
    #pragma unroll
    for (int j = 0; j < 8; ++j) {
        Ua[j] = p.U[wv][ln * QQ + j] * esc;
        Ub[j] = p.U[wv][(ln + 64) * QQ + j] * esc;
    }
    const float cba = p.cb[wv][ln] * esc;
    const float cbb = p.cb[wv][ln + 64] * esc;

    float cst = 0.f;      // cell state, owned by tid<128 (h=tid)
    float hn_last = 0.f;

    if (tid < 128) hbuf[tid + 4 * (tid >> 5)] = 0.f;

    // ---- x staging (wave 3): lane covers col=(ln&31)*4, rows 2j+(ln>>5) ----
    const int xc_col  = (ln & 31) * 4;
    const int xc_half = ln >> 5;
    const int xc_slot = xc_col + 4 * (xc_col >> 5);
    float4 xr[4];
    #pragma unroll
    for (int j = 0; j < 4; ++j) xr[j] = make_float4(0.f, 0.f, 0.f, 0.f);

    if (wv == 3) {  // chunk 0 (steps 0..7), synchronous
        #pragma unroll
        for (int j = 0; j < 4; ++j) {
            const int row = 2 * j + xc_half;
            float4 v = *(const float4*)(p.x + ((size_t)row * BB + bId) * DD + xc_col);
            *(float4*)&xbuf[0][row][xc_slot] = v;
        }
    }
    __syncthreads();

    // ---- preamble zx(0) by waves 2-3 ----
    if (wv >= 2) {
        const float* xrow = &xbuf[0][0][36 * pz];
        float b0 = 0.f, b1 = 0.f, b2 = 0.f, b3 = 0.f;
        #pragma unroll
        for (int i = 0; i < 8; ++i) {
            float4 c4 = *(const float4*)(xrow + 4 * i);
            b0 = fmaf(Wx[4*i+0], c4.x, b0);
            b1 = fmaf(Wx[4*i+1], c4.y, b1);
            b2 = fmaf(Wx[4*i+2], c4.z, b2);
            b3 = fmaf(Wx[4*i+3], c4.w, b3);
        }
        float zx2 = (b0 + b1) + (b2 + b3);
        zx2 += dpp_mov<0xB1>(zx2);
        zx2 += dpp_mov<0x4E>(zx2);
        if ((ln & 3) == 0) zxbuf[0][8 * gz + qz] = zx2;
    }
    __syncthreads();

    #pragma unroll 8
    for (int t = 0; t < TT; ++t) {
        // ---- x prefetch issue (wave 3): 6 steps of slack to consume at E(t|6) ----
        if (((t & 7) == 0) && wv == 3) {
            const int tch = (t >> 3) + 1;
            if (tch < TT / 8) {
                #pragma unroll
                for (int j = 0; j < 4; ++j) {
                    const int row = tch * 8 + 2 * j + xc_half;
                    xr[j] = *(const float4*)(p.x + ((size_t)row * BB + bId) * DD + xc_col);
                }
            }
        }

        // ---- Z: zh = W[wv][qub] . h (4x b128, 16 FMA) + pipelined zx ----
        const float zxs = zxbuf[t & 1][8 * wv + qub];   // broadcast over octet
        const float* hsrc = &hbuf[16 * part8 + 4 * (part8 >> 1)];
        float a0 = 0.f, a1 = 0.f, a2 = 0.f, a3 = 0.f;
        #pragma unroll
        for (int i = 0; i < 4; ++i) {
            float4 c4 = *(const float4*)(hsrc + 4 * i);
            a0 = fmaf(Wh[4*i+0], c4.x, a0);
            a1 = fmaf(Wh[4*i+1], c4.y, a1);
            a2 = fmaf(Wh[4*i+2], c4.z, a2);
            a3 = fmaf(Wh[4*i+3], c4.w, a3);
        }
        float acc = (a0 + a1) + (a2 + a3);
        // 8-lane sum reduce (DPP butterflies)
        acc += dpp_mov<0xB1>(acc);
        acc += dpp_mov<0x4E>(acc);
        acc += dpp_mov<0x141>(acc);
        acc += zxs + breg;

        // ---- Qgate: cos + dual stride-8 product scan (DPP) + readlane bcast ----
        const float cv = __cosf(acc);           // all 8 lanes of octet hold c_q
        float v = cv;
        v *= dpp_mul1<0x118, 0xF>(v);           // row_shr:8 (guard -> *1)
        v *= dpp_mul1<0x142, 0xA>(v);           // row_bcast15 -> rows 1,3
        v *= dpp_mul1<0x143, 0xC>(v);           // row_bcast31 -> rows 2,3
        float u = (ln < 8) ? 1.f : cv;          // scan excluding qubit 0
        u *= dpp_mul1<0x118, 0xF>(u);
        u *= dpp_mul1<0x142, 0xA>(u);
        u *= dpp_mul1<0x143, 0xC>(u);
        const float q0 = RDLANE(u, 63);         // prod_{j>=1} c_j
        const float q1 = RDLANE(v, 8);
        const float q2 = RDLANE(v, 16);
        const float q3 = RDLANE(v, 24);
        const float q4 = RDLANE(v, 32);
        const float q5 = RDLANE(v, 40);
        const float q6 = RDLANE(v, 48);
        const float q7 = RDLANE(v, 56);

        // ---- U expansion (scaled): pre'[gate][h] ----
        float pa = fmaf(Ua[0], q0, cba); float pb = fmaf(Ub[0], q0, cbb);
        pa = fmaf(Ua[1], q1, pa);        pb = fmaf(Ub[1], q1, pb);
        pa = fmaf(Ua[2], q2, pa);        pb = fmaf(Ub[2], q2, pb);
        pa = fmaf(Ua[3], q3, pa);        pb = fmaf(Ub[3], q3, pb);
        pa = fmaf(Ua[4], q4, pa);        pb = fmaf(Ub[4], q4, pb);
        pa = fmaf(Ua[5], q5, pa);        pb = fmaf(Ub[5], q5, pb);
        pa = fmaf(Ua[6], q6, pa);        pb = fmaf(Ub[6], q6, pb);
        pa = fmaf(Ua[7], q7, pa);        pb = fmaf(Ub[7], q7, pb);
        pre[wv * 128 + ln]      = pa;
        pre[wv * 128 + 64 + ln] = pb;

        bar_lds();   // barrier 1: pre[] (+ zxbuf written last E) visible

        // ---- E (waves 0-1) in parallel with zx(t+1) (waves 2-3) ----
        if (tid < 128) {
            // own-gate preact is already in-register (wave0: pa=f@h=ln; wave1: pb=i@h=64+ln)
            float p_f = (wv == 0) ? pa : pre[tid];
            float p_i = (wv == 1) ? pb : pre[128 + tid];
            float p_g = pre[256 + tid];
            float p_o = pre[384 + tid];
            float fg = rcp_f(1.f + exp2_f(p_f));
            float ig = rcp_f(1.f + exp2_f(p_i));
            float gg = 1.f - 2.f * rcp_f(1.f + exp2_f(p_g));
            float og = rcp_f(1.f + exp2_f(p_o));
            cst = fmaf(fg, cst, ig * gg);
            float tc = 1.f - 2.f * rcp_f(1.f + exp2_f(cst * 2.885390081777927f));
            float hn = og * tc;
            hn_last = hn;
            hbuf[tid + 4 * (tid >> 5)] = hn;
            p.out[(size_t)(t * BB + bId) * HH + tid] = hn;  // issue-only
        } else {
            // xbuf refill one chunk-step early (t&7==6) so zx(t+1) at t&7==7 is safe
            if (wv == 3 && (t & 7) == 6) {
                const int tch = (t >> 3) + 1;
                if (tch < TT / 8) {
                    #pragma unroll
                    for (int j = 0; j < 4; ++j) {
                        const int row = 2 * j + xc_half;
                        *(float4*)&xbuf[tch & 1][row][xc_slot] = xr[j];
                    }
                }
            }
            // pipelined zx for step t+1
            if (t < TT - 1) {
                const int tn = t + 1;
                const float* xrow = &xbuf[(tn >> 3) & 1][tn & 7][36 * pz];
                float b0 = 0.f, b1 = 0.f, b2 = 0.f, b3 = 0.f;
                #pragma unroll
                for (int i = 0; i < 8; ++i) {
                    float4 c4 = *(const float4*)(xrow + 4 * i);
                    b0 = fmaf(Wx[4*i+0], c4.x, b0);
                    b1 = fmaf(Wx[4*i+1], c4.y, b1);
                    b2 = fmaf(Wx[4*i+2], c4.z, b2);
                    b3 = fmaf(Wx[4*i+3], c4.w, b3);
                }
                float zx2 = (b0 + b1) + (b2 + b3);
                zx2 += dpp_mov<0xB1>(zx2);
                zx2 += dpp_mov<0x4E>(zx2);
                if ((ln & 3) == 0) zxbuf[tn & 1][8 * gz + qz] = zx2;
            }
        }
        bar_lds();   // barrier 2: hbuf / xbuf / zxbuf ready for next step
    }

    // ---- tail: hx, cx ----
    if (tid < 128) {
        p.out[(size_t)TT * BB * HH + (size_t)bId * HH + tid] = hn_last;
        p.out[(size_t)TT * BB * HH + (size_t)BB * HH + (size_t)bId * HH + tid] = cst;
    }
}

extern "C" void kernel_launch(void* const* d_in, const int* in_sizes, int n_in,
                              void* d_out, int out_size, void* d_ws, size_t ws_size,
                              hipStream_t stream) {
    (void)in_sizes; (void)n_in; (void)out_size; (void)d_ws; (void)ws_size;
    Params p;
    p.x = (const float*)d_in[0];
    for (int g = 0; g < 4; ++g) {
        p.W[g]  = (const float*)d_in[1 + 5 * g + 0];
        p.b[g]  = (const float*)d_in[1 + 5 * g + 1];
        p.th[g] = (const float*)d_in[1 + 5 * g + 2];
        p.U[g]  = (const float*)d_in[1 + 5 * g + 3];
        p.cb[g] = (const float*)d_in[1 + 5 * g + 4];
    }
    p.out = (float*)d_out;
    hipLaunchKernelGGL(qlstm, dim3(BB), dim3(256), 0, stream, p);
}